// Round 10
// baseline (599.938 us; speedup 1.0000x reference)
//
#include <hip/hip_runtime.h>

#define T_STEPS 256
#define BATCH   2048
#define HID     128
#define ROWS    8          // batch rows per block (grid = BATCH/ROWS = 256)
#define BH      (BATCH * HID)

typedef short short8  __attribute__((ext_vector_type(8)));
typedef float float4v __attribute__((ext_vector_type(4)));

__device__ __forceinline__ unsigned short f2bf(float f) {
    unsigned int u = __builtin_bit_cast(unsigned int, f);
    u += 0x7fffu + ((u >> 16) & 1u);
    return (unsigned short)(u >> 16);
}
__device__ __forceinline__ float bf2f(unsigned short b) {
    unsigned int u = ((unsigned int)b) << 16;
    return __builtin_bit_cast(float, u);
}

#if __has_builtin(__builtin_amdgcn_exp2f)
#define EXP2F(x) __builtin_amdgcn_exp2f(x)
#else
#define EXP2F(x) exp2f(x)
#endif
__device__ __forceinline__ float sigf(float x) {
    return __builtin_amdgcn_rcpf(1.0f + EXP2F(x * -1.442695041f));
}
__device__ __forceinline__ float tanh_fast(float x) {
    return 2.0f * __builtin_amdgcn_rcpf(1.0f + EXP2F(x * -2.885390082f)) - 1.0f;
}

// Raw barrier without the vmcnt(0) drain of __syncthreads().
__device__ __forceinline__ void block_sync_lds() {
    asm volatile("s_waitcnt lgkmcnt(0)" ::: "memory");
    __builtin_amdgcn_s_barrier();
    __builtin_amdgcn_sched_barrier(0);
}

// h buffer: [8 rows][256 B], XOR-swizzled, 16-B granule.
__device__ __forceinline__ int lposH(int row, int off) {
    return row * 256 + (off ^ ((row & 7) << 4));
}
// x tile (L1/2): [16 rows][256 B]
__device__ __forceinline__ int lposX(int row, int off) {
    return row * 256 + (off ^ ((row & 7) << 4));
}
// x tile (L0): [16 rows][64 B]
__device__ __forceinline__ int lposX0(int row, int off) {
    return row * 64 + (off ^ ((row & 3) << 4));
}

__device__ __forceinline__ short8 load_w8(const float* __restrict__ p) {
    float4v a = *reinterpret_cast<const float4v*>(p);
    float4v b = *reinterpret_cast<const float4v*>(p + 4);
    short8 r;
    r[0] = (short)f2bf(a[0]); r[1] = (short)f2bf(a[1]);
    r[2] = (short)f2bf(a[2]); r[3] = (short)f2bf(a[3]);
    r[4] = (short)f2bf(b[0]); r[5] = (short)f2bf(b[1]);
    r[6] = (short)f2bf(b[2]); r[7] = (short)f2bf(b[3]);
    return r;
}

#define LDS_BYTES 12288

// One LSTM layer phase. 512 thr (8 waves), 8 rows/block, grid 256 (1/CU).
// Schedule: x-MFMAs de-lumped to 2 K-slices/step into ping-pong xg register
// buffers (xgA/xgB); staging wave-split (waves 0-3: h global write, waves
// 4-7: x load + x-tile ds_write) for per-SIMD role diversity; clamp-not-
// branch prefetch. Numerics identical to r7/r9.
template<bool IS_L0, bool WRITE_H, bool FINAL>
__device__ __forceinline__ void lstm_phase(
    unsigned char* a_lds,
    const float* __restrict__ x0,
    const float* __restrict__ Wih,
    const float* __restrict__ Whh,
    const float* __restrict__ bih,
    const float* __restrict__ bhh,
    unsigned short* __restrict__ hbuf,
    const float* __restrict__ Wfc,
    const float* __restrict__ bfc,
    float* __restrict__ out,
    const int tid, const int b0)
{
    constexpr int XKS = IS_L0 ? 1 : 4;               // x K-slices per 2-step tile
    constexpr int XRB = IS_L0 ? 64 : 256;            // x-tile row bytes
    constexpr int HB  = ROWS * 256;                  // 2048 B per h buffer
    constexpr int XB  = 16 * XRB;                    // x slot bytes
    const int XS0 = 2 * HB, XS1 = 2 * HB + XB;

    const int lane = tid & 63;
    const int wv   = tid >> 6;

    const int t16   = lane & 15;
    const int kgrp8 = (lane >> 4) * 8;
    const int jcol  = 16 * wv + t16;                 // owned gate/h column
    const int row0  = ((lane >> 4) & 1) * 4 + ((lane >> 5) & 1) * 2;

    // h A-frag rows: permuted alias so gates land in acc regs {0,1}
    const int g2   = t16 >> 2;
    const int hrow = ((g2 & 1) << 2) | ((g2 >> 1) << 1) | (t16 & 1);
    int aoffH[4];
    #pragma unroll
    for (int ks = 0; ks < 4; ++ks)
        aoffH[ks] = lposH(hrow, ks * 64 + kgrp8 * 2);
    int aoffX[XKS];
    #pragma unroll
    for (int s = 0; s < XKS; ++s)
        aoffX[s] = IS_L0 ? lposX0(t16, kgrp8 * 2)
                         : lposX(t16, s * 64 + kgrp8 * 2);

    const int hwoff0 = lposH(row0,     2 * jcol);
    const int hwoff1 = lposH(row0 + 1, 2 * jcol);

    // h-writer map (waves 0-3): 256 thr x 8 B cover 8 rows x 256 B
    const int sh_row = (tid >> 5) & 7, sh_c8 = tid & 31;
    const int hroff8 = lposH(sh_row, sh_c8 * 8);
    const size_t sgoff8 = (size_t)(b0 + sh_row) * HID + sh_c8 * 4;   // shorts

    // x-stager map (waves 4-7): 256 thr x 16 B cover 16 tile-rows x 256 B
    const int tid2 = tid & 255;
    const int sar = tid2 >> 4, sc16 = tid2 & 15;
    const int sb  = (sar & 1) | (((sar >> 3) & 1) << 1) | (((sar >> 2) & 1) << 2);
    const int ss  = (sar >> 1) & 1;
    const int xwoff = lposX(sar, sc16 * 16);
    const size_t xgrow = (size_t)(b0 + sb) * HID + sc16 * 8;         // shorts
    // L0: 4 B (2 bf16) per thread, cols 2*sc16, 2*sc16+1 (<24)
    const bool xvalid = (sc16 < 12);
    const int xw0off = lposX0(sar, sc16 * 4);
    const size_t x0row = (size_t)(b0 + sb) * (T_STEPS * 24) + sc16 * 2;

    // ---- weights -> registers ----
    short8 wfh[4][4], wfx[4][XKS];
    float  bias[4];
    #pragma unroll
    for (int q = 0; q < 4; ++q) {
        const int n = 128 * q + jcol;
        bias[q] = bih[n] + bhh[n];
        #pragma unroll
        for (int ks = 0; ks < 4; ++ks)
            wfh[q][ks] = load_w8(Whh + n * 128 + ks * 32 + kgrp8);
        if (IS_L0) {
            if (kgrp8 < 24) wfx[q][0] = load_w8(Wih + n * 24 + kgrp8);
            else            { short8 z = {0,0,0,0,0,0,0,0}; wfx[q][0] = z; }
        } else {
            #pragma unroll
            for (int s = 0; s < 4; ++s)
                wfx[q][s] = load_w8(Wih + n * 128 + s * 32 + kgrp8);
        }
    }

    // zero all LDS (h(-1)=0; L0 x pad cols stay 0)
    {
        short8 z = {0,0,0,0,0,0,0,0};
        #pragma unroll
        for (int i = 0; i < 2; ++i) {
            const int a = tid * 16 + i * 8192;
            if (a < LDS_BYTES)
                *reinterpret_cast<short8*>(&a_lds[a]) = z;
        }
    }
    __syncthreads();

    // ---- prologue staging: xtile[0]={x0,x1}, xtile[1]={x2,x3}; regs={x4,x5}
    short8 xpre = {0,0,0,0,0,0,0,0};
    float2 xpf  = {0.f, 0.f};
    if (tid >= 256) {
        if (!IS_L0) {
            short8 v0 = *reinterpret_cast<const short8*>(&hbuf[(size_t)(0 + ss) * BH + xgrow]);
            short8 v1 = *reinterpret_cast<const short8*>(&hbuf[(size_t)(2 + ss) * BH + xgrow]);
            *reinterpret_cast<short8*>(&a_lds[XS0 + xwoff]) = v0;
            *reinterpret_cast<short8*>(&a_lds[XS1 + xwoff]) = v1;
            xpre = *reinterpret_cast<const short8*>(&hbuf[(size_t)(4 + ss) * BH + xgrow]);
        } else if (xvalid) {
            float2 a = *reinterpret_cast<const float2*>(&x0[x0row + (size_t)(0 + ss) * 24]);
            float2 b = *reinterpret_cast<const float2*>(&x0[x0row + (size_t)(2 + ss) * 24]);
            unsigned int pa, pb;
            asm("v_cvt_pk_bf16_f32 %0, %1, %2" : "=v"(pa) : "v"(a.x), "v"(a.y));
            asm("v_cvt_pk_bf16_f32 %0, %1, %2" : "=v"(pb) : "v"(b.x), "v"(b.y));
            *reinterpret_cast<unsigned int*>(&a_lds[XS0 + xw0off]) = pa;
            *reinterpret_cast<unsigned int*>(&a_lds[XS1 + xw0off]) = pb;
            xpf = *reinterpret_cast<const float2*>(&x0[x0row + (size_t)(4 + ss) * 24]);
        }
    }
    __syncthreads();

    // prologue: xgA = full xg for pair 0 (from xtile slot 0)
    float4v xgA[4], xgB[4];
    #pragma unroll
    for (int q = 0; q < 4; ++q) {
        xgA[q] = float4v{bias[q], bias[q], bias[q], bias[q]};
        xgB[q] = float4v{bias[q], bias[q], bias[q], bias[q]};
    }
    {
        short8 xa[XKS];
        #pragma unroll
        for (int s = 0; s < XKS; ++s)
            xa[s] = *reinterpret_cast<const short8*>(&a_lds[XS0 + aoffX[s]]);
        #pragma unroll
        for (int s = 0; s < XKS; ++s)
            #pragma unroll
            for (int q = 0; q < 4; ++q)
                xgA[q] = __builtin_amdgcn_mfma_f32_16x16x32_bf16(xa[s], wfx[q][s], xgA[q], 0, 0, 0);
    }
    block_sync_lds();   // prologue XS0 reads complete before step-0 XS0 writes

    float creg[2] = {0.f, 0.f};

    // shared epilogue: cell update + h LDS write
    auto cell_write = [&](float4v (&acc)[4], int wb) {
        const float c0 = sigf(acc[1][0]) * creg[0] + sigf(acc[0][0]) * tanh_fast(acc[2][0]);
        const float c1 = sigf(acc[1][1]) * creg[1] + sigf(acc[0][1]) * tanh_fast(acc[2][1]);
        creg[0] = c0;  creg[1] = c1;
        const float h0 = sigf(acc[3][0]) * tanh_fast(c0);
        const float h1 = sigf(acc[3][1]) * tanh_fast(c1);
        unsigned int packed;
        asm("v_cvt_pk_bf16_f32 %0, %1, %2" : "=v"(packed) : "v"(h0), "v"(h1));
        *reinterpret_cast<unsigned short*>(&a_lds[wb + hwoff0]) =
            (unsigned short)(packed & 0xffffu);
        *reinterpret_cast<unsigned short*>(&a_lds[wb + hwoff1]) =
            (unsigned short)(packed >> 16);
    };

    // even step t: rb=0, wb=HB; consume cons regs{0,1}; build slices 0,1 from
    // XRD; stage x-tile(pair p+2) into XST from regs.
    auto stepE = [&](int t, float4v (&cons)[4], float4v (&bld)[4],
                     const int XRD, const int XST) {
        short8 hva[4];
        #pragma unroll
        for (int ks = 0; ks < 4; ++ks)
            hva[ks] = *reinterpret_cast<const short8*>(&a_lds[0 + aoffH[ks]]);
        short8 xa0, xa1;
        if constexpr (!IS_L0) {
            xa0 = *reinterpret_cast<const short8*>(&a_lds[XRD + aoffX[0]]);
            xa1 = *reinterpret_cast<const short8*>(&a_lds[XRD + aoffX[1]]);
        } else {
            xa0 = *reinterpret_cast<const short8*>(&a_lds[XRD + aoffX[0]]);
        }
        float4v acc[4];
        #pragma unroll
        for (int q = 0; q < 4; ++q) {
            const float a = cons[q][0], b = cons[q][1];
            acc[q] = float4v{a, b, a, b};
        }
        if (tid < 256) {                      // h-writer waves
            if (WRITE_H && t > 0) {
                int2 hv = *reinterpret_cast<const int2*>(&a_lds[0 + hroff8]);
                *reinterpret_cast<int2*>(&hbuf[(size_t)(t - 1) * BH + sgoff8]) = hv;
            }
        } else {                              // x-stager waves: ds_write tile
            if constexpr (!IS_L0) {
                *reinterpret_cast<short8*>(&a_lds[XST + xwoff]) = xpre;
            } else {
                if (xvalid) {
                    unsigned int p;
                    asm("v_cvt_pk_bf16_f32 %0, %1, %2" : "=v"(p) : "v"(xpf.x), "v"(xpf.y));
                    *reinterpret_cast<unsigned int*>(&a_lds[XST + xw0off]) = p;
                }
            }
        }
        __builtin_amdgcn_s_setprio(1);
        #pragma unroll
        for (int ks = 0; ks < 4; ++ks)
            #pragma unroll
            for (int q = 0; q < 4; ++q)
                acc[q] = __builtin_amdgcn_mfma_f32_16x16x32_bf16(hva[ks], wfh[q][ks], acc[q], 0, 0, 0);
        #pragma unroll
        for (int q = 0; q < 4; ++q)
            bld[q] = float4v{bias[q], bias[q], bias[q], bias[q]};
        if constexpr (!IS_L0) {
            #pragma unroll
            for (int q = 0; q < 4; ++q)
                bld[q] = __builtin_amdgcn_mfma_f32_16x16x32_bf16(xa0, wfx[q][0], bld[q], 0, 0, 0);
            #pragma unroll
            for (int q = 0; q < 4; ++q)
                bld[q] = __builtin_amdgcn_mfma_f32_16x16x32_bf16(xa1, wfx[q][1], bld[q], 0, 0, 0);
        } else {
            #pragma unroll
            for (int q = 0; q < 4; ++q)
                bld[q] = __builtin_amdgcn_mfma_f32_16x16x32_bf16(xa0, wfx[q][0], bld[q], 0, 0, 0);
        }
        __builtin_amdgcn_s_setprio(0);
        cell_write(acc, HB);
        block_sync_lds();
    };

    // odd step t: rb=HB, wb=0; consume cons regs{2,3}; build slices 2,3;
    // issue global loads for the next staged tile (clamped, unconditional).
    auto stepO = [&](int t, float4v (&cons)[4], float4v (&bld)[4],
                     const int XRD) {
        short8 hva[4];
        #pragma unroll
        for (int ks = 0; ks < 4; ++ks)
            hva[ks] = *reinterpret_cast<const short8*>(&a_lds[HB + aoffH[ks]]);
        short8 xa2, xa3;
        if constexpr (!IS_L0) {
            xa2 = *reinterpret_cast<const short8*>(&a_lds[XRD + aoffX[2]]);
            xa3 = *reinterpret_cast<const short8*>(&a_lds[XRD + aoffX[3]]);
        }
        float4v acc[4];
        #pragma unroll
        for (int q = 0; q < 4; ++q) {
            const float a = cons[q][2], b = cons[q][3];
            acc[q] = float4v{a, b, a, b};
        }
        if (tid < 256) {
            if (WRITE_H) {
                int2 hv = *reinterpret_cast<const int2*>(&a_lds[HB + hroff8]);
                *reinterpret_cast<int2*>(&hbuf[(size_t)(t - 1) * BH + sgoff8]) = hv;
            }
        } else {
            int tl = t + 5 + ss;
            tl = (tl < T_STEPS) ? tl : (T_STEPS - 1);
            if constexpr (!IS_L0) {
                xpre = *reinterpret_cast<const short8*>(&hbuf[(size_t)tl * BH + xgrow]);
            } else {
                if (xvalid)
                    xpf = *reinterpret_cast<const float2*>(&x0[x0row + (size_t)tl * 24]);
            }
        }
        __builtin_amdgcn_s_setprio(1);
        #pragma unroll
        for (int ks = 0; ks < 4; ++ks)
            #pragma unroll
            for (int q = 0; q < 4; ++q)
                acc[q] = __builtin_amdgcn_mfma_f32_16x16x32_bf16(hva[ks], wfh[q][ks], acc[q], 0, 0, 0);
        if constexpr (!IS_L0) {
            #pragma unroll
            for (int q = 0; q < 4; ++q)
                bld[q] = __builtin_amdgcn_mfma_f32_16x16x32_bf16(xa2, wfx[q][2], bld[q], 0, 0, 0);
            #pragma unroll
            for (int q = 0; q < 4; ++q)
                bld[q] = __builtin_amdgcn_mfma_f32_16x16x32_bf16(xa3, wfx[q][3], bld[q], 0, 0, 0);
        }
        __builtin_amdgcn_s_setprio(0);
        cell_write(acc, 0);
        block_sync_lds();
    };

    // 4 steps per iteration so xgA/xgB and x-slot roles are static (rule #20)
    for (int q4 = 0; q4 < T_STEPS / 4; ++q4) {
        const int t0 = 4 * q4;
        stepE(t0,     xgA, xgB, XS1, XS0);
        stepO(t0 + 1, xgA, xgB, XS1);
        stepE(t0 + 2, xgB, xgA, XS0, XS1);
        stepO(t0 + 3, xgB, xgA, XS0);
    }
    // h(255) is in buffer 0
    if (WRITE_H && tid < 256) {
        int2 hv = *reinterpret_cast<const int2*>(&a_lds[0 + hroff8]);
        *reinterpret_cast<int2*>(&hbuf[(size_t)(T_STEPS - 1) * BH + sgoff8]) = hv;
    }
    // fused final FC: out[b] = h_255[b] . Wfc + bfc
    if (FINAL && tid < 128) {
        const int r = tid >> 4, seg = tid & 15;
        float s = 0.f;
        #pragma unroll
        for (int k = 0; k < 8; ++k) {
            const int j = seg * 8 + k;
            s += bf2f(*reinterpret_cast<const unsigned short*>(&a_lds[lposH(r, 2 * j)]))
                 * Wfc[j];
        }
        #pragma unroll
        for (int off = 8; off >= 1; off >>= 1) s += __shfl_xor(s, off);
        if (seg == 0) out[b0 + r] = s + bfc[0];
    }
}

// All 3 layers fused (block-local layer sequencing; hbuf rows are private).
__global__ __launch_bounds__(512, 2)
void lstm3(const float* __restrict__ x0,
           const float* __restrict__ Wih0, const float* __restrict__ Whh0,
           const float* __restrict__ bih0, const float* __restrict__ bhh0,
           const float* __restrict__ Wih1, const float* __restrict__ Whh1,
           const float* __restrict__ bih1, const float* __restrict__ bhh1,
           const float* __restrict__ Wih2, const float* __restrict__ Whh2,
           const float* __restrict__ bih2, const float* __restrict__ bhh2,
           const float* __restrict__ Wfc,  const float* __restrict__ bfc,
           unsigned short* __restrict__ hbuf, float* __restrict__ out)
{
    __shared__ __attribute__((aligned(16))) unsigned char a_lds[LDS_BYTES];
    const int tid = threadIdx.x;
    const int b0  = blockIdx.x * ROWS;

    lstm_phase<true,  true,  false>(a_lds, x0, Wih0, Whh0, bih0, bhh0, hbuf,
                                    nullptr, nullptr, nullptr, tid, b0);
    __syncthreads();
    lstm_phase<false, true,  false>(a_lds, nullptr, Wih1, Whh1, bih1, bhh1, hbuf,
                                    nullptr, nullptr, nullptr, tid, b0);
    __syncthreads();
    lstm_phase<false, false, true >(a_lds, nullptr, Wih2, Whh2, bih2, bhh2, hbuf,
                                    Wfc, bfc, out, tid, b0);
}

extern "C" void kernel_launch(void* const* d_in, const int* in_sizes, int n_in,
                              void* d_out, int out_size, void* d_ws, size_t ws_size,
                              hipStream_t stream) {
    (void)in_sizes; (void)n_in; (void)out_size; (void)ws_size;
    const float* x    = (const float*)d_in[0];
    const float* Wih0 = (const float*)d_in[1];
    const float* Whh0 = (const float*)d_in[2];
    const float* bih0 = (const float*)d_in[3];
    const float* bhh0 = (const float*)d_in[4];
    const float* Wih1 = (const float*)d_in[5];
    const float* Whh1 = (const float*)d_in[6];
    const float* bih1 = (const float*)d_in[7];
    const float* bhh1 = (const float*)d_in[8];
    const float* Wih2 = (const float*)d_in[9];
    const float* Whh2 = (const float*)d_in[10];
    const float* bih2 = (const float*)d_in[11];
    const float* bhh2 = (const float*)d_in[12];
    const float* Wfc  = (const float*)d_in[13];
    const float* bfc  = (const float*)d_in[14];
    float* out = (float*)d_out;
    unsigned short* hbuf = (unsigned short*)d_ws;   // [256][2048][128] bf16 = 134 MB

    dim3 grid(BATCH / ROWS), block(512);
    lstm3<<<grid, block, 0, stream>>>(x, Wih0, Whh0, bih0, bhh0,
                                      Wih1, Whh1, bih1, bhh1,
                                      Wih2, Whh2, bih2, bhh2,
                                      Wfc, bfc, hbuf, out);
}

// Round 11
// 573.364 us; speedup vs baseline: 1.0463x; 1.0463x over previous
//
#include <hip/hip_runtime.h>

#define T_STEPS 256
#define BATCH   2048
#define HID     128
#define ROWS    8          // batch rows per block (grid = BATCH/ROWS = 256)
#define BH      (BATCH * HID)

typedef short short8  __attribute__((ext_vector_type(8)));
typedef float float4v __attribute__((ext_vector_type(4)));

template<int P> struct IntC { static constexpr int value = P; };

__device__ __forceinline__ unsigned short f2bf(float f) {
    unsigned int u = __builtin_bit_cast(unsigned int, f);
    u += 0x7fffu + ((u >> 16) & 1u);
    return (unsigned short)(u >> 16);
}
__device__ __forceinline__ float bf2f(unsigned short b) {
    unsigned int u = ((unsigned int)b) << 16;
    return __builtin_bit_cast(float, u);
}

#if __has_builtin(__builtin_amdgcn_exp2f)
#define EXP2F(x) __builtin_amdgcn_exp2f(x)
#else
#define EXP2F(x) exp2f(x)
#endif
__device__ __forceinline__ float sigf(float x) {
    return __builtin_amdgcn_rcpf(1.0f + EXP2F(x * -1.442695041f));
}
__device__ __forceinline__ float tanh_fast(float x) {
    return 2.0f * __builtin_amdgcn_rcpf(1.0f + EXP2F(x * -2.885390082f)) - 1.0f;
}

// Raw barrier without the vmcnt(0) drain of __syncthreads().
__device__ __forceinline__ void block_sync_lds() {
    asm volatile("s_waitcnt lgkmcnt(0)" ::: "memory");
    __builtin_amdgcn_s_barrier();
    __builtin_amdgcn_sched_barrier(0);
}

// h buffer: [8 rows][256 B], XOR-swizzled, 16-B granule.
__device__ __forceinline__ int lposH(int row, int off) {
    return row * 256 + (off ^ ((row & 7) << 4));
}
// x tile (L1/2): [16 rows][256 B]
__device__ __forceinline__ int lposX(int row, int off) {
    return row * 256 + (off ^ ((row & 7) << 4));
}
// x tile (L0): [16 rows][64 B]
__device__ __forceinline__ int lposX0(int row, int off) {
    return row * 64 + (off ^ ((row & 3) << 4));
}

__device__ __forceinline__ short8 load_w8(const float* __restrict__ p) {
    float4v a = *reinterpret_cast<const float4v*>(p);
    float4v b = *reinterpret_cast<const float4v*>(p + 4);
    short8 r;
    r[0] = (short)f2bf(a[0]); r[1] = (short)f2bf(a[1]);
    r[2] = (short)f2bf(a[2]); r[3] = (short)f2bf(a[3]);
    r[4] = (short)f2bf(b[0]); r[5] = (short)f2bf(b[1]);
    r[6] = (short)f2bf(b[2]); r[7] = (short)f2bf(b[3]);
    return r;
}

#define LDS_BYTES 12288

// One LSTM layer phase. 512 thr (8 waves), 8 rows/block, grid 256 (1/CU).
// Post-barrier critical path: h ds_read -> 16-MFMA h-chain -> trans -> h
// ds_write. ALL x-work (slot ds_reads + x-MFMAs) lives in the step TAIL
// (pre-barrier): slot data was staged 3 steps earlier, so tails overlap
// other waves' trans phases. Stagers: loads at even steps, slot ds_writes
// at odd steps (always the slot tails are NOT reading that step).
template<bool IS_L0, bool WRITE_H, bool FINAL>
__device__ __forceinline__ void lstm_phase(
    unsigned char* a_lds,
    const float* __restrict__ x0,
    const float* __restrict__ Wih,
    const float* __restrict__ Whh,
    const float* __restrict__ bih,
    const float* __restrict__ bhh,
    unsigned short* __restrict__ hbuf,
    const float* __restrict__ Wfc,
    const float* __restrict__ bfc,
    float* __restrict__ out,
    const int tid, const int b0)
{
    constexpr int XKS = IS_L0 ? 1 : 4;               // x K-slices per 2-step tile
    constexpr int XRB = IS_L0 ? 64 : 256;            // x-tile row bytes
    constexpr int HB  = ROWS * 256;                  // 2048 B per h buffer
    constexpr int XB  = 16 * XRB;                    // x slot bytes
    const int XS0 = 2 * HB, XS1 = 2 * HB + XB;

    const int lane = tid & 63;
    const int wv   = tid >> 6;

    const int t16   = lane & 15;
    const int kgrp8 = (lane >> 4) * 8;
    const int jcol  = 16 * wv + t16;                 // owned gate/h column
    const int row0  = ((lane >> 4) & 1) * 4 + ((lane >> 5) & 1) * 2;

    // h A-frag rows: permuted alias so gates land in acc regs {0,1}
    const int g2   = t16 >> 2;
    const int hrow = ((g2 & 1) << 2) | ((g2 >> 1) << 1) | (t16 & 1);
    int aoffH[4];
    #pragma unroll
    for (int ks = 0; ks < 4; ++ks)
        aoffH[ks] = lposH(hrow, ks * 64 + kgrp8 * 2);
    int aoffX[XKS];
    #pragma unroll
    for (int s = 0; s < XKS; ++s)
        aoffX[s] = IS_L0 ? lposX0(t16, kgrp8 * 2)
                         : lposX(t16, s * 64 + kgrp8 * 2);

    const int hwoff0 = lposH(row0,     2 * jcol);
    const int hwoff1 = lposH(row0 + 1, 2 * jcol);

    // h-writer map (waves 0-3): 256 thr x 8 B cover 8 rows x 256 B
    const int sh_row = (tid >> 5) & 7, sh_c8 = tid & 31;
    const int hroff8 = lposH(sh_row, sh_c8 * 8);
    const size_t sgoff8 = (size_t)(b0 + sh_row) * HID + sh_c8 * 4;   // shorts

    // x-stager map (waves 4-7): 256 thr x 16 B cover 16 tile-rows x 256 B
    const int tid2 = tid & 255;
    const int sar = tid2 >> 4, sc16 = tid2 & 15;
    const int sb  = (sar & 1) | (((sar >> 3) & 1) << 1) | (((sar >> 2) & 1) << 2);
    const int ss  = (sar >> 1) & 1;
    const int xwoff = lposX(sar, sc16 * 16);
    const size_t xgrow = (size_t)(b0 + sb) * HID + sc16 * 8;         // shorts
    // L0: 4 B (2 bf16) per thread, cols 2*sc16, 2*sc16+1 (<24)
    const bool xvalid = (sc16 < 12);
    const int xw0off = lposX0(sar, sc16 * 4);
    const size_t x0row = (size_t)(b0 + sb) * (T_STEPS * 24) + sc16 * 2;

    // ---- weights -> registers ----
    short8 wfh[4][4], wfx[4][XKS];
    float  bias[4];
    #pragma unroll
    for (int q = 0; q < 4; ++q) {
        const int n = 128 * q + jcol;
        bias[q] = bih[n] + bhh[n];
        #pragma unroll
        for (int ks = 0; ks < 4; ++ks)
            wfh[q][ks] = load_w8(Whh + n * 128 + ks * 32 + kgrp8);
        if (IS_L0) {
            if (kgrp8 < 24) wfx[q][0] = load_w8(Wih + n * 24 + kgrp8);
            else            { short8 z = {0,0,0,0,0,0,0,0}; wfx[q][0] = z; }
        } else {
            #pragma unroll
            for (int s = 0; s < 4; ++s)
                wfx[q][s] = load_w8(Wih + n * 128 + s * 32 + kgrp8);
        }
    }

    // zero all LDS (h(-1)=0; L0 x pad cols stay 0)
    {
        short8 z = {0,0,0,0,0,0,0,0};
        #pragma unroll
        for (int i = 0; i < 2; ++i) {
            const int a = tid * 16 + i * 8192;
            if (a < LDS_BYTES)
                *reinterpret_cast<short8*>(&a_lds[a]) = z;
        }
    }
    __syncthreads();

    // ---- prologue staging: S0={x0,x1}, S1={x2,x3}; regs <- {x4,x5} ----
    short8 xpre = {0,0,0,0,0,0,0,0};
    float2 xpf  = {0.f, 0.f};
    if (tid >= 256) {
        if (!IS_L0) {
            short8 v0 = *reinterpret_cast<const short8*>(&hbuf[(size_t)(0 + ss) * BH + xgrow]);
            short8 v1 = *reinterpret_cast<const short8*>(&hbuf[(size_t)(2 + ss) * BH + xgrow]);
            *reinterpret_cast<short8*>(&a_lds[XS0 + xwoff]) = v0;
            *reinterpret_cast<short8*>(&a_lds[XS1 + xwoff]) = v1;
            xpre = *reinterpret_cast<const short8*>(&hbuf[(size_t)(4 + ss) * BH + xgrow]);
        } else if (xvalid) {
            float2 a = *reinterpret_cast<const float2*>(&x0[x0row + (size_t)(0 + ss) * 24]);
            float2 b = *reinterpret_cast<const float2*>(&x0[x0row + (size_t)(2 + ss) * 24]);
            unsigned int pa, pb;
            asm("v_cvt_pk_bf16_f32 %0, %1, %2" : "=v"(pa) : "v"(a.x), "v"(a.y));
            asm("v_cvt_pk_bf16_f32 %0, %1, %2" : "=v"(pb) : "v"(b.x), "v"(b.y));
            *reinterpret_cast<unsigned int*>(&a_lds[XS0 + xw0off]) = pa;
            *reinterpret_cast<unsigned int*>(&a_lds[XS1 + xw0off]) = pb;
            xpf = *reinterpret_cast<const float2*>(&x0[x0row + (size_t)(4 + ss) * 24]);
        }
    }
    __syncthreads();

    // prologue: xgA = full xg for pair 0 (from S0). First S0 overwrite is at
    // step 1 (post-barrier-0), so these reads are safe.
    float4v xgA[4], xgB[4];
    #pragma unroll
    for (int q = 0; q < 4; ++q) {
        xgA[q] = float4v{bias[q], bias[q], bias[q], bias[q]};
        xgB[q] = float4v{bias[q], bias[q], bias[q], bias[q]};
    }
    {
        short8 xa[XKS];
        #pragma unroll
        for (int s = 0; s < XKS; ++s)
            xa[s] = *reinterpret_cast<const short8*>(&a_lds[XS0 + aoffX[s]]);
        #pragma unroll
        for (int s = 0; s < XKS; ++s)
            #pragma unroll
            for (int q = 0; q < 4; ++q)
                xgA[q] = __builtin_amdgcn_mfma_f32_16x16x32_bf16(xa[s], wfx[q][s], xgA[q], 0, 0, 0);
    }

    float creg[2] = {0.f, 0.f};

    // POS 0..3 within a 4-step macro (t = 4m+POS):
    //  POS0: cons xgA{0,1}; tail builds xgB slices 0,1 from XS1; stagers load
    //  POS1: cons xgA{2,3}; tail xgB slices 2,3 (XS1); stagers ds_write->XS0
    //  POS2: cons xgB{0,1}; tail rebuilds xgA slices 0,1 from XS0; stagers load
    //  POS3: cons xgB{2,3}; tail xgA slices 2,3 (XS0); stagers ds_write->XS1
    auto do_step = [&](int t, auto PC) {
        constexpr int POS = decltype(PC)::value;
        constexpr bool EVEN = (POS & 1) == 0;
        const int rb = EVEN ? 0 : HB;
        const int wb = EVEN ? HB : 0;
        float4v (&cons)[4] = (POS < 2) ? xgA : xgB;
        float4v (&bld)[4]  = (POS < 2) ? xgB : xgA;
        const int XRD = (POS < 2) ? XS1 : XS0;
        const int XWR = (POS == 1) ? XS0 : XS1;      // stager write slot (odd POS)

        // 1: h A-frag ds_reads (critical path head)
        short8 hva[4];
        #pragma unroll
        for (int ks = 0; ks < 4; ++ks)
            hva[ks] = *reinterpret_cast<const short8*>(&a_lds[rb + aoffH[ks]]);
        // 2: acc init from pipelined xg
        float4v acc[4];
        #pragma unroll
        for (int q = 0; q < 4; ++q) {
            const float a = EVEN ? cons[q][0] : cons[q][2];
            const float b = EVEN ? cons[q][1] : cons[q][3];
            acc[q] = float4v{a, b, a, b};
        }
        // 3: wave-split staging (off critical path)
        if (tid < 256) {                              // h-writer waves
            if (WRITE_H && t > 0) {
                int2 hv = *reinterpret_cast<const int2*>(&a_lds[rb + hroff8]);
                *reinterpret_cast<int2*>(&hbuf[(size_t)(t - 1) * BH + sgoff8]) = hv;
            }
        } else {                                      // x-stager waves
            if constexpr (EVEN) {
                int tl = t + 4 + ss;
                tl = (tl < T_STEPS) ? tl : (T_STEPS - 1);
                if constexpr (!IS_L0) {
                    xpre = *reinterpret_cast<const short8*>(&hbuf[(size_t)tl * BH + xgrow]);
                } else {
                    if (xvalid)
                        xpf = *reinterpret_cast<const float2*>(&x0[x0row + (size_t)tl * 24]);
                }
            } else {
                if constexpr (!IS_L0) {
                    *reinterpret_cast<short8*>(&a_lds[XWR + xwoff]) = xpre;
                } else {
                    if (xvalid) {
                        unsigned int p;
                        asm("v_cvt_pk_bf16_f32 %0, %1, %2" : "=v"(p) : "v"(xpf.x), "v"(xpf.y));
                        *reinterpret_cast<unsigned int*>(&a_lds[XWR + xw0off]) = p;
                    }
                }
            }
        }
        // 4: h-MFMA chain (critical path), prio 1
        __builtin_amdgcn_s_setprio(1);
        #pragma unroll
        for (int ks = 0; ks < 4; ++ks)
            #pragma unroll
            for (int q = 0; q < 4; ++q)
                acc[q] = __builtin_amdgcn_mfma_f32_16x16x32_bf16(hva[ks], wfh[q][ks], acc[q], 0, 0, 0);
        __builtin_amdgcn_s_setprio(0);
        // 5: cell update + h LDS write (end of critical path)
        {
            const float c0 = sigf(acc[1][0]) * creg[0] + sigf(acc[0][0]) * tanh_fast(acc[2][0]);
            const float c1 = sigf(acc[1][1]) * creg[1] + sigf(acc[0][1]) * tanh_fast(acc[2][1]);
            creg[0] = c0;  creg[1] = c1;
            const float h0 = sigf(acc[3][0]) * tanh_fast(c0);
            const float h1 = sigf(acc[3][1]) * tanh_fast(c1);
            unsigned int packed;
            asm("v_cvt_pk_bf16_f32 %0, %1, %2" : "=v"(packed) : "v"(h0), "v"(h1));
            *reinterpret_cast<unsigned short*>(&a_lds[wb + hwoff0]) =
                (unsigned short)(packed & 0xffffu);
            *reinterpret_cast<unsigned short*>(&a_lds[wb + hwoff1]) =
                (unsigned short)(packed >> 16);
        }
        // 6: TAIL — x ds_reads + x-MFMAs (pre-barrier; slot staged 3 steps
        //    ago; overlaps other waves' phases 4-5)
        if constexpr (!IS_L0) {
            if constexpr (EVEN) {
                short8 xa0 = *reinterpret_cast<const short8*>(&a_lds[XRD + aoffX[0]]);
                short8 xa1 = *reinterpret_cast<const short8*>(&a_lds[XRD + aoffX[1]]);
                #pragma unroll
                for (int q = 0; q < 4; ++q)
                    bld[q] = float4v{bias[q], bias[q], bias[q], bias[q]};
                #pragma unroll
                for (int q = 0; q < 4; ++q)
                    bld[q] = __builtin_amdgcn_mfma_f32_16x16x32_bf16(xa0, wfx[q][0], bld[q], 0, 0, 0);
                #pragma unroll
                for (int q = 0; q < 4; ++q)
                    bld[q] = __builtin_amdgcn_mfma_f32_16x16x32_bf16(xa1, wfx[q][1], bld[q], 0, 0, 0);
            } else {
                short8 xa2 = *reinterpret_cast<const short8*>(&a_lds[XRD + aoffX[2]]);
                short8 xa3 = *reinterpret_cast<const short8*>(&a_lds[XRD + aoffX[3]]);
                #pragma unroll
                for (int q = 0; q < 4; ++q)
                    bld[q] = __builtin_amdgcn_mfma_f32_16x16x32_bf16(xa2, wfx[q][2], bld[q], 0, 0, 0);
                #pragma unroll
                for (int q = 0; q < 4; ++q)
                    bld[q] = __builtin_amdgcn_mfma_f32_16x16x32_bf16(xa3, wfx[q][3], bld[q], 0, 0, 0);
            }
        } else {
            if constexpr (EVEN) {
                short8 xa0 = *reinterpret_cast<const short8*>(&a_lds[XRD + aoffX[0]]);
                #pragma unroll
                for (int q = 0; q < 4; ++q)
                    bld[q] = float4v{bias[q], bias[q], bias[q], bias[q]};
                #pragma unroll
                for (int q = 0; q < 4; ++q)
                    bld[q] = __builtin_amdgcn_mfma_f32_16x16x32_bf16(xa0, wfx[q][0], bld[q], 0, 0, 0);
            }
        }
        // 7: single raw barrier
        block_sync_lds();
    };

    for (int m = 0; m < T_STEPS / 4; ++m) {
        const int t0 = 4 * m;
        do_step(t0,     IntC<0>{});
        do_step(t0 + 1, IntC<1>{});
        do_step(t0 + 2, IntC<2>{});
        do_step(t0 + 3, IntC<3>{});
    }
    // h(255) is in buffer 0
    if (WRITE_H && tid < 256) {
        int2 hv = *reinterpret_cast<const int2*>(&a_lds[0 + hroff8]);
        *reinterpret_cast<int2*>(&hbuf[(size_t)(T_STEPS - 1) * BH + sgoff8]) = hv;
    }
    // fused final FC: out[b] = h_255[b] . Wfc + bfc
    if (FINAL && tid < 128) {
        const int r = tid >> 4, seg = tid & 15;
        float s = 0.f;
        #pragma unroll
        for (int k = 0; k < 8; ++k) {
            const int j = seg * 8 + k;
            s += bf2f(*reinterpret_cast<const unsigned short*>(&a_lds[lposH(r, 2 * j)]))
                 * Wfc[j];
        }
        #pragma unroll
        for (int off = 8; off >= 1; off >>= 1) s += __shfl_xor(s, off);
        if (seg == 0) out[b0 + r] = s + bfc[0];
    }
}

// All 3 layers fused (block-local layer sequencing; hbuf rows are private).
__global__ __launch_bounds__(512, 2)
void lstm3(const float* __restrict__ x0,
           const float* __restrict__ Wih0, const float* __restrict__ Whh0,
           const float* __restrict__ bih0, const float* __restrict__ bhh0,
           const float* __restrict__ Wih1, const float* __restrict__ Whh1,
           const float* __restrict__ bih1, const float* __restrict__ bhh1,
           const float* __restrict__ Wih2, const float* __restrict__ Whh2,
           const float* __restrict__ bih2, const float* __restrict__ bhh2,
           const float* __restrict__ Wfc,  const float* __restrict__ bfc,
           unsigned short* __restrict__ hbuf, float* __restrict__ out)
{
    __shared__ __attribute__((aligned(16))) unsigned char a_lds[LDS_BYTES];
    const int tid = threadIdx.x;
    const int b0  = blockIdx.x * ROWS;

    lstm_phase<true,  true,  false>(a_lds, x0, Wih0, Whh0, bih0, bhh0, hbuf,
                                    nullptr, nullptr, nullptr, tid, b0);
    __syncthreads();
    lstm_phase<false, true,  false>(a_lds, nullptr, Wih1, Whh1, bih1, bhh1, hbuf,
                                    nullptr, nullptr, nullptr, tid, b0);
    __syncthreads();
    lstm_phase<false, false, true >(a_lds, nullptr, Wih2, Whh2, bih2, bhh2, hbuf,
                                    Wfc, bfc, out, tid, b0);
}

extern "C" void kernel_launch(void* const* d_in, const int* in_sizes, int n_in,
                              void* d_out, int out_size, void* d_ws, size_t ws_size,
                              hipStream_t stream) {
    (void)in_sizes; (void)n_in; (void)out_size; (void)ws_size;
    const float* x    = (const float*)d_in[0];
    const float* Wih0 = (const float*)d_in[1];
    const float* Whh0 = (const float*)d_in[2];
    const float* bih0 = (const float*)d_in[3];
    const float* bhh0 = (const float*)d_in[4];
    const float* Wih1 = (const float*)d_in[5];
    const float* Whh1 = (const float*)d_in[6];
    const float* bih1 = (const float*)d_in[7];
    const float* bhh1 = (const float*)d_in[8];
    const float* Wih2 = (const float*)d_in[9];
    const float* Whh2 = (const float*)d_in[10];
    const float* bih2 = (const float*)d_in[11];
    const float* bhh2 = (const float*)d_in[12];
    const float* Wfc  = (const float*)d_in[13];
    const float* bfc  = (const float*)d_in[14];
    float* out = (float*)d_out;
    unsigned short* hbuf = (unsigned short*)d_ws;   // [256][2048][128] bf16 = 134 MB

    dim3 grid(BATCH / ROWS), block(512);
    lstm3<<<grid, block, 0, stream>>>(x, Wih0, Whh0, bih0, bhh0,
                                      Wih1, Whh1, bih1, bhh1,
                                      Wih2, Whh2, bih2, bhh2,
                                      Wfc, bfc, hbuf, out);
}